// Round 1
// baseline (304.260 us; speedup 1.0000x reference)
//
#include <hip/hip_runtime.h>

#define B_ 8
#define T_ 2048
#define C_ 1024
#define D_ 128
#define M_ (B_*T_)   // 16384

typedef __attribute__((ext_vector_type(4))) float f32x4;
typedef __attribute__((ext_vector_type(8))) short s16x8;

static __device__ __forceinline__ ushort f2bf(float f){
  unsigned u = __float_as_uint(f);
  u = (u + 0x7fffu + ((u >> 16) & 1u)) >> 16;   // RNE
  return (ushort)u;
}

static __device__ __forceinline__ unsigned cvt_pk_bf16(float lo, float hi){
  unsigned r;
  asm volatile("v_cvt_pk_bf16_f32 %0, %1, %2" : "=v"(r) : "v"(lo), "v"(hi));
  return r;
}

// ---------------------------------------------------------------------------
// Kernel 1: prep — x f32 -> bf16 (contiguous), W{q,k,v} -> wt[384][1024] bf16
// col regions: 0-127 = q (Wq), 128-255 = k (Wk), 256-383 = v (Wv)
// ---------------------------------------------------------------------------
__global__ __launch_bounds__(256) void prep_kernel(
    const float* __restrict__ x,
    const float* __restrict__ Wk, const float* __restrict__ Wq, const float* __restrict__ Wv,
    ushort* __restrict__ xbf, ushort* __restrict__ wt)
{
  int bid = blockIdx.x, tid = threadIdx.x;
  if (bid < 8192) {
    int idx = bid * 256 + tid;               // 8 floats per thread, 2,097,152 threads exact
    const float4* xp = (const float4*)x;
    float4 a = xp[idx * 2], b = xp[idx * 2 + 1];
    uint4 st;
    st.x = (unsigned)f2bf(a.x) | ((unsigned)f2bf(a.y) << 16);
    st.y = (unsigned)f2bf(a.z) | ((unsigned)f2bf(a.w) << 16);
    st.z = (unsigned)f2bf(b.x) | ((unsigned)f2bf(b.y) << 16);
    st.w = (unsigned)f2bf(b.z) | ((unsigned)f2bf(b.w) << 16);
    ((uint4*)xbf)[idx] = st;
  } else {
    int j = (bid - 8192) * 256 + tid;        // 393,216 = 384*1024
    if (j < 384 * 1024) {
      int n3 = j >> 10, k = j & 1023;
      int sel = n3 >> 7, n = n3 & 127;
      const float* W = (sel == 0) ? Wq : (sel == 1) ? Wk : Wv;
      wt[j] = f2bf(W[k * 128 + n]);          // wt[n3][k] = W[k][n]
    }
  }
}

// ---------------------------------------------------------------------------
// Kernel 2: qkv GEMM + RoPE epilogue.
// Block: 512 thr (8 waves = 2m x 4n), tile 64x384, BK=64.
// A (x bf16) staged via global_load_lds w/ XOR swizzle (src pre-swizzled).
// B (wt) fragments read direct from global (L2-resident, 768 KB).
// ---------------------------------------------------------------------------
__global__ __launch_bounds__(512) void qkv_kernel(
    const ushort* __restrict__ xbf, const ushort* __restrict__ wt,
    const float* __restrict__ cosp, const float* __restrict__ sinp,
    ushort* __restrict__ Qw, ushort* __restrict__ Kw, ushort* __restrict__ VT)
{
  __shared__ __align__(16) ushort As[64 * 64];   // 64 rows x 64 bf16 (128 B rows), 8 KB
  const int tid = threadIdx.x;
  const int m0  = blockIdx.x * 64;
  const int wid = tid >> 6, lane = tid & 63;
  const int wm = wid >> 2, wn = wid & 3;
  const int g = lane >> 4, l15 = lane & 15;

  f32x4 acc[2][6];
  #pragma unroll
  for (int i = 0; i < 2; i++)
    #pragma unroll
    for (int j = 0; j < 6; j++) acc[i][j] = f32x4{0.f, 0.f, 0.f, 0.f};

  // staging: thread t fills LDS bytes [t*16, t*16+16); source column pre-swizzled
  const int o = tid * 16;
  const int srow = o >> 7;
  const int scb  = (o & 127) ^ ((srow & 7) << 4);
  const char* xbase = (const char*)xbf + (size_t)(m0 + srow) * 2048 + scb;

  for (int k0 = 0; k0 < 1024; k0 += 64) {
    __builtin_amdgcn_global_load_lds(
        (const __attribute__((address_space(1))) void*)(xbase + k0 * 2),
        (__attribute__((address_space(3))) void*)((char*)As + o), 16, 0, 0);
    __syncthreads();
    #pragma unroll
    for (int kk = 0; kk < 2; kk++) {
      s16x8 af[2];
      #pragma unroll
      for (int mi = 0; mi < 2; mi++) {
        int row = wm * 32 + mi * 16 + l15;
        int cb  = (kk * 64 + g * 16) ^ ((row & 7) << 4);
        af[mi] = *(const s16x8*)((const char*)As + row * 128 + cb);
      }
      s16x8 bfr[6];
      #pragma unroll
      for (int n = 0; n < 6; n++) {
        int col = wn * 96 + n * 16 + l15;
        bfr[n] = *(const s16x8*)(wt + col * 1024 + k0 + kk * 32 + g * 8);
      }
      #pragma unroll
      for (int mi = 0; mi < 2; mi++)
        #pragma unroll
        for (int n = 0; n < 6; n++)
          acc[mi][n] = __builtin_amdgcn_mfma_f32_16x16x32_bf16(af[mi], bfr[n], acc[mi][n], 0, 0, 0);
    }
    __syncthreads();
  }

  // epilogue: C frag = (row = m0+wm*32+mi*16+g*4+r, col = wn*96+n*16+l15)
  const int rowb0 = m0 + wm * 32;
  #pragma unroll
  for (int mi = 0; mi < 2; mi++) {
    #pragma unroll
    for (int n = 0; n < 6; n++) {
      int colbase = wn * 96 + n * 16;
      int region  = colbase >> 7;            // 0=q 1=k 2=v
      int dcol    = (colbase & 127) + l15;   // 0..127 within region
      int rowb    = rowb0 + mi * 16 + g * 4;
      if (region < 2) {
        ushort* dst = region ? Kw : Qw;
        int ii = dcol >> 1;
        float sgn = (dcol & 1) ? 1.0f : -1.0f;
        #pragma unroll
        for (int r = 0; r < 4; r++) {
          float own  = acc[mi][n][r];
          float part = __shfl_xor(own, 1, 64);   // partner col (even<->odd)
          int row = rowb + r;
          int t   = row & 2047;
          float c = cosp[t * 64 + ii], s = sinp[t * 64 + ii];
          float val = own * c + sgn * part * s;  // even: e*c - o*s ; odd: o*c + e*s
          dst[row * 128 + dcol] = f2bf(val);
        }
      } else {
        int t0 = rowb & 2047;
        int b  = rowb >> 11;
        unsigned w0 = (unsigned)f2bf(acc[mi][n][0]) | ((unsigned)f2bf(acc[mi][n][1]) << 16);
        unsigned w1 = (unsigned)f2bf(acc[mi][n][2]) | ((unsigned)f2bf(acc[mi][n][3]) << 16);
        uint2 st; st.x = w0; st.y = w1;
        *(uint2*)(VT + (size_t)b * (128 * 2048) + dcol * 2048 + t0) = st;  // VT[b][d][t]
      }
    }
  }
}

// ---------------------------------------------------------------------------
// Kernel 3: causal flash attention. 1 wave per 16 q rows. Swapped QK^T:
// S^T = mfma(A=K, B=Q) -> lane holds S[q=l15][kv = h*16 + g*4 + r].
// PV: O^T = mfma(A=V^T, B=P^T) after 8-shuffle P remap.
// ---------------------------------------------------------------------------
__global__ __launch_bounds__(64) void attn_kernel(
    const ushort* __restrict__ Qw, const ushort* __restrict__ Kw,
    const ushort* __restrict__ VT, float* __restrict__ out)
{
  const int lane = threadIdx.x;
  const int g = lane >> 4, l15 = lane & 15;
  const int w  = blockIdx.x;
  const int b  = w >> 7;
  const int q0 = (w & 127) << 4;
  const int qg = q0 + l15;
  const ushort* Qb = Qw + (size_t)b * T_ * 128;
  const ushort* Kb = Kw + (size_t)b * T_ * 128;
  const ushort* Vb = VT + (size_t)b * 128 * T_;

  s16x8 qf[4];
  #pragma unroll
  for (int kd = 0; kd < 4; kd++)
    qf[kd] = *(const s16x8*)(Qb + qg * 128 + kd * 32 + g * 8);

  f32x4 acco[8];
  #pragma unroll
  for (int i = 0; i < 8; i++) acco[i] = f32x4{0.f, 0.f, 0.f, 0.f};
  float mrun = -1e30f, lrun = 0.0f;
  const float scale = 0.08838834764831845f;   // 1/sqrt(128)

  const int nt = (q0 + 47) >> 5;              // kv tiles of 32, causal
  for (int tI = 0; tI < nt; tI++) {
    int kv0 = tI * 32;
    f32x4 accs[2] = { f32x4{0.f,0.f,0.f,0.f}, f32x4{0.f,0.f,0.f,0.f} };
    #pragma unroll
    for (int h = 0; h < 2; h++)
      #pragma unroll
      for (int kd = 0; kd < 4; kd++) {
        s16x8 kf = *(const s16x8*)(Kb + (kv0 + h * 16 + l15) * 128 + kd * 32 + g * 8);
        accs[h] = __builtin_amdgcn_mfma_f32_16x16x32_bf16(kf, qf[kd], accs[h], 0, 0, 0);
      }

    float p[2][4];
    float pmax = -1e30f;
    #pragma unroll
    for (int h = 0; h < 2; h++)
      #pragma unroll
      for (int r = 0; r < 4; r++) {
        int kvg = kv0 + h * 16 + g * 4 + r;
        float sv = accs[h][r] * scale;
        sv = (kvg <= qg) ? sv : -1e30f;
        p[h][r] = sv;
        pmax = fmaxf(pmax, sv);
      }
    pmax = fmaxf(pmax, __shfl_xor(pmax, 16, 64));
    pmax = fmaxf(pmax, __shfl_xor(pmax, 32, 64));
    float mnew = fmaxf(mrun, pmax);
    float f = __expf(mrun - mnew);
    float psum = 0.0f;
    #pragma unroll
    for (int h = 0; h < 2; h++)
      #pragma unroll
      for (int r = 0; r < 4; r++) { float e = __expf(p[h][r] - mnew); p[h][r] = e; psum += e; }
    psum += __shfl_xor(psum, 16, 64);
    psum += __shfl_xor(psum, 32, 64);
    lrun = lrun * f + psum;
    mrun = mnew;
    #pragma unroll
    for (int i = 0; i < 8; i++) acco[i] *= f;

    // P (S^T C-layout) -> bf16 B-fragment: lane needs P^T[kv=g*8+j][q=l15], j=0..7
    unsigned v0 = cvt_pk_bf16(p[0][0], p[0][1]);
    unsigned v1 = cvt_pk_bf16(p[0][2], p[0][3]);
    unsigned v2 = cvt_pk_bf16(p[1][0], p[1][1]);
    unsigned v3 = cvt_pk_bf16(p[1][2], p[1][3]);
    unsigned pb[4];
    #pragma unroll
    for (int wd = 0; wd < 4; wd++) {
      int src = (((g & 1) * 2 + (wd >> 1)) << 4) + l15;   // gs*16 + q
      unsigned t0 = __shfl((wd & 1) ? v1 : v0, src, 64);  // h=0 source words
      unsigned t1 = __shfl((wd & 1) ? v3 : v2, src, 64);  // h=1 source words
      pb[wd] = (g < 2) ? t0 : t1;                         // h = g>>1
    }
    s16x8 pbv = *(s16x8*)pb;

    #pragma unroll
    for (int dt = 0; dt < 8; dt++) {
      s16x8 vf = *(const s16x8*)(Vb + (dt * 16 + l15) * 2048 + kv0 + g * 8);
      acco[dt] = __builtin_amdgcn_mfma_f32_16x16x32_bf16(vf, pbv, acco[dt], 0, 0, 0);
    }
  }

  float inv = 1.0f / lrun;
  float* ob = out + ((size_t)b * T_ + qg) * 128;
  #pragma unroll
  for (int dt = 0; dt < 8; dt++) {
    f32x4 o4 = acco[dt] * inv;   // O^T frag: row d = dt*16+g*4+r, col q = l15
    *(f32x4*)(ob + dt * 16 + g * 4) = o4;
  }
}

// ---------------------------------------------------------------------------
extern "C" void kernel_launch(void* const* d_in, const int* in_sizes, int n_in,
                              void* d_out, int out_size, void* d_ws, size_t ws_size,
                              hipStream_t stream)
{
  const float* x    = (const float*)d_in[0];
  const float* cosp = (const float*)d_in[1];
  const float* sinp = (const float*)d_in[2];
  const float* Wk   = (const float*)d_in[3];
  const float* Wq   = (const float*)d_in[4];
  const float* Wv   = (const float*)d_in[5];
  char* ws = (char*)d_ws;
  ushort* xbf = (ushort*)ws;                         // 33,554,432 B
  ushort* wt  = (ushort*)(ws + 33554432);            //    786,432 B
  ushort* Qw  = (ushort*)(ws + 34340864);            //  4,194,304 B
  ushort* Kw  = (ushort*)(ws + 38535168);            //  4,194,304 B
  ushort* VT  = (ushort*)(ws + 42729472);            //  4,194,304 B
  float* outp = (float*)d_out;

  prep_kernel<<<9728, 256, 0, stream>>>(x, Wk, Wq, Wv, xbf, wt);
  qkv_kernel<<<256, 512, 0, stream>>>(xbf, wt, cosp, sinp, Qw, Kw, VT);
  attn_kernel<<<1024, 64, 0, stream>>>(Qw, Kw, VT, outp);
}

// Round 2
// 213.109 us; speedup vs baseline: 1.4277x; 1.4277x over previous
//
#include <hip/hip_runtime.h>

#define B_ 8
#define T_ 2048
#define C_ 1024
#define D_ 128
#define M_ (B_*T_)   // 16384

typedef __attribute__((ext_vector_type(4))) float f32x4;
typedef __attribute__((ext_vector_type(8))) short s16x8;

static __device__ __forceinline__ ushort f2bf(float f){
  unsigned u = __float_as_uint(f);
  u = (u + 0x7fffu + ((u >> 16) & 1u)) >> 16;   // RNE
  return (ushort)u;
}
static __device__ __forceinline__ float bf2f(ushort u){
  return __uint_as_float(((unsigned)u) << 16);
}
static __device__ __forceinline__ unsigned cvt_pk_bf16(float lo, float hi){
  unsigned r;
  asm volatile("v_cvt_pk_bf16_f32 %0, %1, %2" : "=v"(r) : "v"(lo), "v"(hi));
  return r;
}

// ---------------------------------------------------------------------------
// Kernel 1: prep — x f32 -> bf16 (contiguous), W{q,k,v} -> wt[384][1024] bf16
// ---------------------------------------------------------------------------
__global__ __launch_bounds__(256) void prep_kernel(
    const float* __restrict__ x,
    const float* __restrict__ Wk, const float* __restrict__ Wq, const float* __restrict__ Wv,
    ushort* __restrict__ xbf, ushort* __restrict__ wt)
{
  int bid = blockIdx.x, tid = threadIdx.x;
  if (bid < 8192) {
    int idx = bid * 256 + tid;
    const float4* xp = (const float4*)x;
    float4 a = xp[idx * 2], b = xp[idx * 2 + 1];
    uint4 st;
    st.x = (unsigned)f2bf(a.x) | ((unsigned)f2bf(a.y) << 16);
    st.y = (unsigned)f2bf(a.z) | ((unsigned)f2bf(a.w) << 16);
    st.z = (unsigned)f2bf(b.x) | ((unsigned)f2bf(b.y) << 16);
    st.w = (unsigned)f2bf(b.z) | ((unsigned)f2bf(b.w) << 16);
    ((uint4*)xbf)[idx] = st;
  } else {
    int j = (bid - 8192) * 256 + tid;
    if (j < 384 * 1024) {
      int n3 = j >> 10, k = j & 1023;
      int sel = n3 >> 7, n = n3 & 127;
      const float* W = (sel == 0) ? Wq : (sel == 1) ? Wk : Wv;
      wt[j] = f2bf(W[k * 128 + n]);          // wt[n3][k] = W[k][n]
    }
  }
}

// ---------------------------------------------------------------------------
// Kernel 2: qkv GEMM + RoPE epilogue. 512 thr (8 waves = 2m x 4n),
// tile 64x384, BK=64. Both A and B staged via global_load_lds (XOR swizzle,
// source pre-swizzled per rule 21). Fixes round-1's strided L2 B-frag reads.
// ---------------------------------------------------------------------------
__global__ __launch_bounds__(512) void qkv_kernel(
    const ushort* __restrict__ xbf, const ushort* __restrict__ wt,
    const float* __restrict__ cosp, const float* __restrict__ sinp,
    ushort* __restrict__ Qw, ushort* __restrict__ Kw, ushort* __restrict__ VT)
{
  __shared__ __align__(16) ushort As[64 * 64];    //  8 KB
  __shared__ __align__(16) ushort Bs[384 * 64];   // 48 KB
  const int tid = threadIdx.x;
  const int m0  = blockIdx.x * 64;
  const int wid = tid >> 6, lane = tid & 63;
  const int wm = wid >> 2, wn = wid & 3;
  const int g = lane >> 4, l15 = lane & 15;

  f32x4 acc[2][6];
  #pragma unroll
  for (int i = 0; i < 2; i++)
    #pragma unroll
    for (int j = 0; j < 6; j++) acc[i][j] = f32x4{0.f, 0.f, 0.f, 0.f};

  // staging geometry: thread t fills LDS bytes [t*16, t*16+16)
  const int o = tid * 16;
  const int srow = o >> 7;                    // row within a 64-row panel
  const int scb  = (o & 127) ^ ((srow & 7) << 4);
  const char* xbase = (const char*)xbf + (size_t)(m0 + srow) * 2048 + scb;
  // B: 6 panels of 64 cols; row j*64+srow has (row&7)==(srow&7) since 64%8==0
  const char* wbase = (const char*)wt + (size_t)srow * 2048 + scb;

  for (int k0 = 0; k0 < 1024; k0 += 64) {
    __builtin_amdgcn_global_load_lds(
        (const __attribute__((address_space(1))) void*)(xbase + k0 * 2),
        (__attribute__((address_space(3))) void*)((char*)As + o), 16, 0, 0);
    #pragma unroll
    for (int j = 0; j < 6; j++) {
      __builtin_amdgcn_global_load_lds(
          (const __attribute__((address_space(1))) void*)(wbase + (size_t)j * 64 * 2048 + k0 * 2),
          (__attribute__((address_space(3))) void*)((char*)Bs + j * 8192 + o), 16, 0, 0);
    }
    __syncthreads();
    #pragma unroll
    for (int kk = 0; kk < 2; kk++) {
      s16x8 af[2];
      #pragma unroll
      for (int mi = 0; mi < 2; mi++) {
        int row = wm * 32 + mi * 16 + l15;
        int cb  = (kk * 64 + g * 16) ^ ((row & 7) << 4);
        af[mi] = *(const s16x8*)((const char*)As + row * 128 + cb);
      }
      s16x8 bfr[6];
      #pragma unroll
      for (int n = 0; n < 6; n++) {
        int col = wn * 96 + n * 16 + l15;
        int cb2 = (kk * 64 + g * 16) ^ ((col & 7) << 4);
        bfr[n] = *(const s16x8*)((const char*)Bs + col * 128 + cb2);
      }
      #pragma unroll
      for (int mi = 0; mi < 2; mi++)
        #pragma unroll
        for (int n = 0; n < 6; n++)
          acc[mi][n] = __builtin_amdgcn_mfma_f32_16x16x32_bf16(af[mi], bfr[n], acc[mi][n], 0, 0, 0);
    }
    __syncthreads();
  }

  // epilogue: C frag = (row = m0+wm*32+mi*16+g*4+r, col = wn*96+n*16+l15)
  const int rowb0 = m0 + wm * 32;
  #pragma unroll
  for (int mi = 0; mi < 2; mi++) {
    #pragma unroll
    for (int n = 0; n < 6; n++) {
      int colbase = wn * 96 + n * 16;
      int region  = colbase >> 7;            // 0=q 1=k 2=v
      int dcol    = (colbase & 127) + l15;
      int rowb    = rowb0 + mi * 16 + g * 4;
      if (region < 2) {
        ushort* dst = region ? Kw : Qw;
        int ii = dcol >> 1;
        float sgn = (dcol & 1) ? 1.0f : -1.0f;
        #pragma unroll
        for (int r = 0; r < 4; r++) {
          float own  = acc[mi][n][r];
          float part = __shfl_xor(own, 1, 64);
          int row = rowb + r;
          int t   = row & 2047;
          float c = cosp[t * 64 + ii], s = sinp[t * 64 + ii];
          float val = own * c + sgn * part * s;
          dst[row * 128 + dcol] = f2bf(val);
        }
      } else {
        int t0 = rowb & 2047;
        int b  = rowb >> 11;
        unsigned w0 = (unsigned)f2bf(acc[mi][n][0]) | ((unsigned)f2bf(acc[mi][n][1]) << 16);
        unsigned w1 = (unsigned)f2bf(acc[mi][n][2]) | ((unsigned)f2bf(acc[mi][n][3]) << 16);
        uint2 st; st.x = w0; st.y = w1;
        *(uint2*)(VT + (size_t)b * (128 * 2048) + dcol * 2048 + t0) = st;  // VT[b][d][t]
      }
    }
  }
}

// ---------------------------------------------------------------------------
// Kernel 3: split-KV causal flash attention.
// Work item = (batch b, q-tile of 16 rows, kv-chunk of 256). 4608 blocks.
// Writes l-normalized bf16 partial O + (m,l) per q-row; combine merges.
// ---------------------------------------------------------------------------
#define TILE_STEP(T_IDX, KF_CUR, KF_NXT)  do {                                   \
    int kv0 = kv_base + (T_IDX) * 32;                                            \
    s16x8 vf[8];                                                                 \
    _Pragma("unroll")                                                            \
    for (int dt = 0; dt < 8; dt++)                                               \
      vf[dt] = *(const s16x8*)(Vb + (size_t)(dt * 16 + l15) * 2048 + kv0 + g * 8);\
    f32x4 accs[2] = { f32x4{0.f,0.f,0.f,0.f}, f32x4{0.f,0.f,0.f,0.f} };          \
    _Pragma("unroll")                                                            \
    for (int h = 0; h < 2; h++)                                                  \
      _Pragma("unroll")                                                          \
      for (int kd = 0; kd < 4; kd++)                                             \
        accs[h] = __builtin_amdgcn_mfma_f32_16x16x32_bf16(KF_CUR[h*4+kd], qf[kd], accs[h], 0, 0, 0); \
    if ((T_IDX) + 1 < nt) {                                                      \
      int kvn = kv0 + 32;                                                        \
      _Pragma("unroll")                                                          \
      for (int h = 0; h < 2; h++)                                                \
        _Pragma("unroll")                                                        \
        for (int kd = 0; kd < 4; kd++)                                           \
          KF_NXT[h*4+kd] = *(const s16x8*)(Kb + (size_t)(kvn + h*16 + l15) * 128 + kd*32 + g*8); \
    }                                                                            \
    float p[2][4];                                                               \
    float pmax = -1e30f;                                                         \
    _Pragma("unroll")                                                            \
    for (int h = 0; h < 2; h++)                                                  \
      _Pragma("unroll")                                                          \
      for (int r = 0; r < 4; r++) {                                              \
        int kvg = kv0 + h * 16 + g * 4 + r;                                      \
        float sv = accs[h][r] * scale;                                           \
        sv = (kvg <= qg) ? sv : -1e30f;                                          \
        p[h][r] = sv;                                                            \
        pmax = fmaxf(pmax, sv);                                                  \
      }                                                                          \
    pmax = fmaxf(pmax, __shfl_xor(pmax, 16, 64));                                \
    pmax = fmaxf(pmax, __shfl_xor(pmax, 32, 64));                                \
    float mnew = fmaxf(mrun, pmax);                                              \
    float f = __expf(mrun - mnew);                                               \
    float psum = 0.0f;                                                           \
    _Pragma("unroll")                                                            \
    for (int h = 0; h < 2; h++)                                                  \
      _Pragma("unroll")                                                          \
      for (int r = 0; r < 4; r++) { float e = __expf(p[h][r] - mnew); p[h][r] = e; psum += e; } \
    psum += __shfl_xor(psum, 16, 64);                                            \
    psum += __shfl_xor(psum, 32, 64);                                            \
    lrun = lrun * f + psum;                                                      \
    mrun = mnew;                                                                 \
    _Pragma("unroll")                                                            \
    for (int i = 0; i < 8; i++) acco[i] *= f;                                    \
    unsigned v0 = cvt_pk_bf16(p[0][0], p[0][1]);                                 \
    unsigned v1 = cvt_pk_bf16(p[0][2], p[0][3]);                                 \
    unsigned v2 = cvt_pk_bf16(p[1][0], p[1][1]);                                 \
    unsigned v3 = cvt_pk_bf16(p[1][2], p[1][3]);                                 \
    unsigned pb[4];                                                              \
    _Pragma("unroll")                                                            \
    for (int wd = 0; wd < 4; wd++) {                                             \
      int src = (((g & 1) * 2 + (wd >> 1)) << 4) + l15;                          \
      unsigned t0 = __shfl((wd & 1) ? v1 : v0, src, 64);                         \
      unsigned t1 = __shfl((wd & 1) ? v3 : v2, src, 64);                         \
      pb[wd] = (g < 2) ? t0 : t1;                                                \
    }                                                                            \
    s16x8 pbv = *(s16x8*)pb;                                                     \
    _Pragma("unroll")                                                            \
    for (int dt = 0; dt < 8; dt++)                                               \
      acco[dt] = __builtin_amdgcn_mfma_f32_16x16x32_bf16(vf[dt], pbv, acco[dt], 0, 0, 0); \
  } while (0)

__global__ __launch_bounds__(64) void attn_kernel(
    const ushort* __restrict__ Qw, const ushort* __restrict__ Kw,
    const ushort* __restrict__ VT, ushort* __restrict__ Opart,
    float* __restrict__ Ml)
{
  const int lane = threadIdx.x;
  const int g = lane >> 4, l15 = lane & 15;
  const int bid = blockIdx.x;
  const int b   = bid / 576;
  const int idx = bid - b * 576;
  int gg = 0;
  #pragma unroll
  for (int t = 1; t < 8; t++) if (idx >= 8 * t * (t + 1)) gg = t;
  const int r0 = idx - 8 * gg * (gg + 1);
  const int qt_in = r0 / (gg + 1);
  const int c  = r0 - qt_in * (gg + 1);
  const int qt = gg * 16 + qt_in;
  const int q0 = qt * 16;
  const int kv_base = c * 256;
  const int kv_end  = min(kv_base + 256, q0 + 16);
  const int nt = (kv_end - kv_base + 31) >> 5;
  const int qg = q0 + l15;

  const ushort* Qb = Qw + (size_t)b * T_ * 128;
  const ushort* Kb = Kw + (size_t)b * T_ * 128;
  const ushort* Vb = VT + (size_t)b * 128 * T_;

  s16x8 qf[4];
  #pragma unroll
  for (int kd = 0; kd < 4; kd++)
    qf[kd] = *(const s16x8*)(Qb + qg * 128 + kd * 32 + g * 8);

  f32x4 acco[8];
  #pragma unroll
  for (int i = 0; i < 8; i++) acco[i] = f32x4{0.f, 0.f, 0.f, 0.f};
  float mrun = -1e30f, lrun = 0.0f;
  const float scale = 0.08838834764831845f;   // 1/sqrt(128)

  s16x8 kfA[8], kfB[8];
  #pragma unroll
  for (int h = 0; h < 2; h++)
    #pragma unroll
    for (int kd = 0; kd < 4; kd++)
      kfA[h*4+kd] = *(const s16x8*)(Kb + (size_t)(kv_base + h*16 + l15) * 128 + kd*32 + g*8);

  for (int t = 0; t < nt; t += 2) {
    TILE_STEP(t, kfA, kfB);
    if (t + 1 < nt) TILE_STEP(t + 1, kfB, kfA);
  }

  // store l-normalized partial (bf16) + (m,l)
  const int s = bid;           // == b*576 + idx
  float inv = 1.0f / lrun;
  ushort* ob = Opart + (size_t)s * 2048 + l15 * 128;
  #pragma unroll
  for (int dt = 0; dt < 8; dt++) {
    f32x4 o4 = acco[dt] * inv;
    unsigned w0 = cvt_pk_bf16(o4[0], o4[1]);
    unsigned w1 = cvt_pk_bf16(o4[2], o4[3]);
    uint2 st; st.x = w0; st.y = w1;
    *(uint2*)(ob + dt * 16 + g * 4) = st;    // O[q=l15][d=dt*16+g*4 ..+3]
  }
  if (lane < 16) {
    Ml[(size_t)s * 32 + lane * 2]     = mrun;
    Ml[(size_t)s * 32 + lane * 2 + 1] = lrun;
  }
}

// ---------------------------------------------------------------------------
// Kernel 4: combine partials. One block (256 thr) per (b, q-tile).
// ---------------------------------------------------------------------------
__global__ __launch_bounds__(256) void combine_kernel(
    const ushort* __restrict__ Opart, const float* __restrict__ Ml,
    float* __restrict__ out)
{
  const int bq = blockIdx.x;          // 0..1023
  const int b = bq >> 7, qt = bq & 127;
  const int gg = qt >> 4, nch = gg + 1;
  const int idx0 = 8 * gg * (gg + 1) + (qt - gg * 16) * nch;
  const int s0 = b * 576 + idx0;
  const int tid = threadIdx.x;
  const int row = tid >> 4, ci = tid & 15;

  float M = -1e30f;
  for (int c = 0; c < nch; c++)
    M = fmaxf(M, Ml[(size_t)(s0 + c) * 32 + row * 2]);

  float acc[8];
  #pragma unroll
  for (int j = 0; j < 8; j++) acc[j] = 0.f;
  float W = 0.f;
  for (int c = 0; c < nch; c++) {
    float m = Ml[(size_t)(s0 + c) * 32 + row * 2];
    float l = Ml[(size_t)(s0 + c) * 32 + row * 2 + 1];
    float w = l * __expf(m - M);
    W += w;
    s16x8 v = *(const s16x8*)(Opart + (size_t)(s0 + c) * 2048 + row * 128 + ci * 8);
    #pragma unroll
    for (int j = 0; j < 8; j++) acc[j] += w * bf2f((ushort)v[j]);
  }
  float invW = 1.0f / W;
  float* op = out + ((size_t)(b * 2048 + qt * 16 + row)) * 128 + ci * 8;
  f32x4 o0 { acc[0]*invW, acc[1]*invW, acc[2]*invW, acc[3]*invW };
  f32x4 o1 { acc[4]*invW, acc[5]*invW, acc[6]*invW, acc[7]*invW };
  *(f32x4*)op = o0;
  *(f32x4*)(op + 4) = o1;
}

// ---------------------------------------------------------------------------
extern "C" void kernel_launch(void* const* d_in, const int* in_sizes, int n_in,
                              void* d_out, int out_size, void* d_ws, size_t ws_size,
                              hipStream_t stream)
{
  const float* x    = (const float*)d_in[0];
  const float* cosp = (const float*)d_in[1];
  const float* sinp = (const float*)d_in[2];
  const float* Wk   = (const float*)d_in[3];
  const float* Wq   = (const float*)d_in[4];
  const float* Wv   = (const float*)d_in[5];
  char* ws = (char*)d_ws;
  ushort* xbf   = (ushort*)ws;                       // 33,554,432 B (dead after qkv)
  ushort* wt    = (ushort*)(ws + 33554432);          //    786,432 B
  ushort* Qw    = (ushort*)(ws + 34340864);          //  4,194,304 B
  ushort* Kw    = (ushort*)(ws + 38535168);          //  4,194,304 B
  ushort* VT    = (ushort*)(ws + 42729472);          //  4,194,304 B
  ushort* Opart = (ushort*)ws;                       // 18,874,368 B (aliases xbf)
  float*  Ml    = (float*)(ws + 18874368);           //    589,824 B (still in xbf)
  float* outp = (float*)d_out;

  prep_kernel<<<9728, 256, 0, stream>>>(x, Wk, Wq, Wv, xbf, wt);
  qkv_kernel<<<256, 512, 0, stream>>>(xbf, wt, cosp, sinp, Qw, Kw, VT);
  attn_kernel<<<4608, 64, 0, stream>>>(Qw, Kw, VT, Opart, Ml);
  combine_kernel<<<1024, 256, 0, stream>>>(Opart, Ml, outp);
}

// Round 3
// 175.578 us; speedup vs baseline: 1.7329x; 1.2138x over previous
//
#include <hip/hip_runtime.h>

#define B_ 8
#define T_ 2048
#define C_ 1024
#define D_ 128
#define M_ (B_*T_)   // 16384

typedef __attribute__((ext_vector_type(4))) float f32x4;
typedef __attribute__((ext_vector_type(8))) short s16x8;

static __device__ __forceinline__ ushort f2bf(float f){
  unsigned u = __float_as_uint(f);
  u = (u + 0x7fffu + ((u >> 16) & 1u)) >> 16;   // RNE
  return (ushort)u;
}
static __device__ __forceinline__ float bf2f(ushort u){
  return __uint_as_float(((unsigned)u) << 16);
}
static __device__ __forceinline__ unsigned cvt_pk_bf16(float lo, float hi){
  unsigned r;
  asm volatile("v_cvt_pk_bf16_f32 %0, %1, %2" : "=v"(r) : "v"(lo), "v"(hi));
  return r;
}

// ---------------------------------------------------------------------------
// Kernel 1: prep — x f32 -> bf16 (contiguous), W{q,k,v} -> wt[384][1024] bf16
// ---------------------------------------------------------------------------
__global__ __launch_bounds__(256) void prep_kernel(
    const float* __restrict__ x,
    const float* __restrict__ Wk, const float* __restrict__ Wq, const float* __restrict__ Wv,
    ushort* __restrict__ xbf, ushort* __restrict__ wt)
{
  int bid = blockIdx.x, tid = threadIdx.x;
  if (bid < 8192) {
    int idx = bid * 256 + tid;
    const float4* xp = (const float4*)x;
    float4 a = xp[idx * 2], b = xp[idx * 2 + 1];
    uint4 st;
    st.x = (unsigned)f2bf(a.x) | ((unsigned)f2bf(a.y) << 16);
    st.y = (unsigned)f2bf(a.z) | ((unsigned)f2bf(a.w) << 16);
    st.z = (unsigned)f2bf(b.x) | ((unsigned)f2bf(b.y) << 16);
    st.w = (unsigned)f2bf(b.z) | ((unsigned)f2bf(b.w) << 16);
    ((uint4*)xbf)[idx] = st;
  } else {
    int j = (bid - 8192) * 256 + tid;
    if (j < 384 * 1024) {
      int n3 = j >> 10, k = j & 1023;
      int sel = n3 >> 7, n = n3 & 127;
      const float* W = (sel == 0) ? Wq : (sel == 1) ? Wk : Wv;
      wt[j] = f2bf(W[k * 128 + n]);          // wt[n3][k] = W[k][n]
    }
  }
}

// ---------------------------------------------------------------------------
// Kernel 2: qkv GEMM + RoPE epilogue. 512 thr (8 waves = 2m x 4n),
// tile 64x384, BK=64, DOUBLE-BUFFERED: stage(t+1) issued before compute(t),
// vmcnt drained only at the end-of-iter barrier -> loads overlap MFMA.
// ---------------------------------------------------------------------------
__global__ __launch_bounds__(512) void qkv_kernel(
    const ushort* __restrict__ xbf, const ushort* __restrict__ wt,
    const float* __restrict__ cosp, const float* __restrict__ sinp,
    ushort* __restrict__ Qw, ushort* __restrict__ Kw, ushort* __restrict__ VT)
{
  __shared__ __align__(16) ushort As[2][64 * 64];    // 2 x  8 KB
  __shared__ __align__(16) ushort Bs[2][384 * 64];   // 2 x 48 KB
  const int tid = threadIdx.x;
  const int m0  = blockIdx.x * 64;
  const int wid = tid >> 6, lane = tid & 63;
  const int wm = wid >> 2, wn = wid & 3;
  const int g = lane >> 4, l15 = lane & 15;

  f32x4 acc[2][6];
  #pragma unroll
  for (int i = 0; i < 2; i++)
    #pragma unroll
    for (int j = 0; j < 6; j++) acc[i][j] = f32x4{0.f, 0.f, 0.f, 0.f};

  const int o = tid * 16;
  const int srow = o >> 7;
  const int scb  = (o & 127) ^ ((srow & 7) << 4);
  const char* xbase = (const char*)xbf + (size_t)(m0 + srow) * 2048 + scb;
  const char* wbase = (const char*)wt + (size_t)srow * 2048 + scb;

  auto stage = [&](int k0, int bb) {
    __builtin_amdgcn_global_load_lds(
        (const __attribute__((address_space(1))) void*)(xbase + k0 * 2),
        (__attribute__((address_space(3))) void*)((char*)As + bb * 8192 + o), 16, 0, 0);
    #pragma unroll
    for (int j = 0; j < 6; j++) {
      __builtin_amdgcn_global_load_lds(
          (const __attribute__((address_space(1))) void*)(wbase + (size_t)j * 64 * 2048 + k0 * 2),
          (__attribute__((address_space(3))) void*)((char*)Bs + bb * 49152 + j * 8192 + o), 16, 0, 0);
    }
  };

  stage(0, 0);
  __syncthreads();
  int bb = 0;
  for (int k0 = 0; k0 < 1024; k0 += 64) {
    if (k0 + 64 < 1024) stage(k0 + 64, bb ^ 1);
    const char* Ab = (const char*)As + bb * 8192;
    const char* Bb = (const char*)Bs + bb * 49152;
    #pragma unroll
    for (int kk = 0; kk < 2; kk++) {
      s16x8 af[2];
      #pragma unroll
      for (int mi = 0; mi < 2; mi++) {
        int row = wm * 32 + mi * 16 + l15;
        int cb  = (kk * 64 + g * 16) ^ ((row & 7) << 4);
        af[mi] = *(const s16x8*)(Ab + row * 128 + cb);
      }
      s16x8 bfr[6];
      #pragma unroll
      for (int n = 0; n < 6; n++) {
        int col = wn * 96 + n * 16 + l15;
        int cb2 = (kk * 64 + g * 16) ^ ((col & 7) << 4);
        bfr[n] = *(const s16x8*)(Bb + col * 128 + cb2);
      }
      __builtin_amdgcn_s_setprio(1);
      #pragma unroll
      for (int mi = 0; mi < 2; mi++)
        #pragma unroll
        for (int n = 0; n < 6; n++)
          acc[mi][n] = __builtin_amdgcn_mfma_f32_16x16x32_bf16(af[mi], bfr[n], acc[mi][n], 0, 0, 0);
      __builtin_amdgcn_s_setprio(0);
    }
    __syncthreads();
    bb ^= 1;
  }

  // epilogue: C frag = (row = m0+wm*32+mi*16+g*4+r, col = wn*96+n*16+l15)
  const int rowb0 = m0 + wm * 32;
  #pragma unroll
  for (int mi = 0; mi < 2; mi++) {
    #pragma unroll
    for (int n = 0; n < 6; n++) {
      int colbase = wn * 96 + n * 16;
      int region  = colbase >> 7;            // 0=q 1=k 2=v
      int dcol    = (colbase & 127) + l15;
      int rowb    = rowb0 + mi * 16 + g * 4;
      if (region < 2) {
        ushort* dst = region ? Kw : Qw;
        int ii = dcol >> 1;
        float sgn = (dcol & 1) ? 1.0f : -1.0f;
        #pragma unroll
        for (int r = 0; r < 4; r++) {
          float own  = acc[mi][n][r];
          float part = __shfl_xor(own, 1, 64);
          int row = rowb + r;
          int t   = row & 2047;
          float c = cosp[t * 64 + ii], s = sinp[t * 64 + ii];
          float val = own * c + sgn * part * s;
          dst[row * 128 + dcol] = f2bf(val);
        }
      } else {
        int t0 = rowb & 2047;
        int b  = rowb >> 11;
        unsigned w0 = (unsigned)f2bf(acc[mi][n][0]) | ((unsigned)f2bf(acc[mi][n][1]) << 16);
        unsigned w1 = (unsigned)f2bf(acc[mi][n][2]) | ((unsigned)f2bf(acc[mi][n][3]) << 16);
        uint2 st; st.x = w0; st.y = w1;
        *(uint2*)(VT + (size_t)b * (128 * 2048) + dcol * 2048 + t0) = st;  // VT[b][d][t]
      }
    }
  }
}

// ---------------------------------------------------------------------------
// Kernel 3: split-KV causal flash attention, 4-wave blocks.
// Block = (batch b, q-block of 64 rows [16/wave], kv-chunk of 256).
// K and V^T double-buffered in LDS (XOR-swizzled, staged via global_load_lds
// with inverse-swizzled source), KVBLK=64 per tile. 1152 blocks.
// ---------------------------------------------------------------------------
__global__ __launch_bounds__(256) void attn_kernel(
    const ushort* __restrict__ Qw, const ushort* __restrict__ Kw,
    const ushort* __restrict__ VT, ushort* __restrict__ Opart,
    float* __restrict__ Ml)
{
  __shared__ __align__(16) ushort KVs[2][16384];   // per buf: K 8192 ush, V 8192 ush (32 KB)
  const int tid = threadIdx.x;
  const int w = tid >> 6, lane = tid & 63;
  const int g = lane >> 4, l15 = lane & 15;

  const int bid = blockIdx.x;
  const int b   = bid / 144;
  const int idx = bid - b * 144;
  int a = 0;
  #pragma unroll
  for (int t = 1; t < 8; t++) if (idx >= 2 * t * (t + 1)) a = t;
  const int rem = idx - 2 * a * (a + 1);
  const int jin = rem / (a + 1);
  const int c   = rem - jin * (a + 1);
  const int j   = a * 4 + jin;
  const int q0  = j * 64;
  const int kv_base = c * 256;
  const int kv_end  = min(kv_base + 256, q0 + 64);
  const int nt  = (kv_end - kv_base) >> 6;     // 1..4 full 64-row tiles
  const int qg  = q0 + w * 16 + l15;

  const ushort* Qb = Qw + (size_t)b * T_ * 128;
  const char* Kbase = (const char*)(Kw + (size_t)b * T_ * 128);
  const char* Vbase = (const char*)(VT + (size_t)b * 128 * T_);

  auto stage = [&](int kv0, int bbuf) {
    char* Kd = (char*)&KVs[bbuf][0];
    char* Vd = (char*)&KVs[bbuf][8192];
    #pragma unroll
    for (int p = 0; p < 4; p++) {           // K: 64 rows x 256B, swizzled
      int oo = p * 4096 + tid * 16;
      int r = oo >> 8, cin = oo & 255;
      int cb = cin ^ ((r & 7) << 4);
      __builtin_amdgcn_global_load_lds(
          (const __attribute__((address_space(1))) void*)(Kbase + (size_t)(kv0 + r) * 256 + cb),
          (__attribute__((address_space(3))) void*)(Kd + oo), 16, 0, 0);
    }
    #pragma unroll
    for (int p = 0; p < 4; p++) {           // V^T: 128 rows x 128B, swizzled
      int oo = p * 4096 + tid * 16;
      int r = oo >> 7, cin = oo & 127;
      int cb = cin ^ ((r & 7) << 4);
      __builtin_amdgcn_global_load_lds(
          (const __attribute__((address_space(1))) void*)(Vbase + (size_t)r * 4096 + (size_t)kv0 * 2 + cb),
          (__attribute__((address_space(3))) void*)(Vd + oo), 16, 0, 0);
    }
  };

  s16x8 qf[4];
  #pragma unroll
  for (int kd = 0; kd < 4; kd++)
    qf[kd] = *(const s16x8*)(Qb + qg * 128 + kd * 32 + g * 8);

  f32x4 acco[8];
  #pragma unroll
  for (int i = 0; i < 8; i++) acco[i] = f32x4{0.f, 0.f, 0.f, 0.f};
  float mrun = -1e30f, lrun = 0.0f;
  const float scale = 0.08838834764831845f;   // 1/sqrt(128)

  stage(kv_base, 0);
  __syncthreads();
  int bbuf = 0;
  for (int t = 0; t < nt; t++) {
    int kv0 = kv_base + t * 64;
    if (t + 1 < nt) stage(kv0 + 64, bbuf ^ 1);
    const char* Kd = (const char*)&KVs[bbuf][0];
    const char* Vd = (const char*)&KVs[bbuf][8192];

    // QK^T (swapped): accs[h] = S^T[kv=h*16+g*4+r][q=l15]
    f32x4 accs[4];
    #pragma unroll
    for (int h = 0; h < 4; h++) accs[h] = f32x4{0.f, 0.f, 0.f, 0.f};
    __builtin_amdgcn_s_setprio(1);
    #pragma unroll
    for (int h = 0; h < 4; h++) {
      int rr = h * 16 + l15;
      int rs = rr * 256;
      int sw = (rr & 7) << 4;
      #pragma unroll
      for (int kd = 0; kd < 4; kd++) {
        s16x8 kf = *(const s16x8*)(Kd + rs + ((kd * 64 + g * 16) ^ sw));
        accs[h] = __builtin_amdgcn_mfma_f32_16x16x32_bf16(kf, qf[kd], accs[h], 0, 0, 0);
      }
    }
    __builtin_amdgcn_s_setprio(0);

    // online softmax over 64 kv values (16 per lane; reduce across g via shfl)
    float p[4][4];
    float pmax = -1e30f;
    #pragma unroll
    for (int h = 0; h < 4; h++)
      #pragma unroll
      for (int r = 0; r < 4; r++) {
        int kvg = kv0 + h * 16 + g * 4 + r;
        float sv = accs[h][r] * scale;
        sv = (kvg <= qg) ? sv : -1e30f;
        p[h][r] = sv;
        pmax = fmaxf(pmax, sv);
      }
    pmax = fmaxf(pmax, __shfl_xor(pmax, 16, 64));
    pmax = fmaxf(pmax, __shfl_xor(pmax, 32, 64));
    float mnew = fmaxf(mrun, pmax);
    float f = __expf(mrun - mnew);
    float psum = 0.0f;
    #pragma unroll
    for (int h = 0; h < 4; h++)
      #pragma unroll
      for (int r = 0; r < 4; r++) { float e = __expf(p[h][r] - mnew); p[h][r] = e; psum += e; }
    psum += __shfl_xor(psum, 16, 64);
    psum += __shfl_xor(psum, 32, 64);
    lrun = lrun * f + psum;
    mrun = mnew;
    #pragma unroll
    for (int i = 0; i < 8; i++) acco[i] *= f;

    // P remap -> two B-fragments (kv 0..31 and 32..63 of the tile)
    unsigned pbw[2][4];
    #pragma unroll
    for (int hk = 0; hk < 2; hk++) {
      unsigned v0 = cvt_pk_bf16(p[2 * hk][0], p[2 * hk][1]);
      unsigned v1 = cvt_pk_bf16(p[2 * hk][2], p[2 * hk][3]);
      unsigned v2 = cvt_pk_bf16(p[2 * hk + 1][0], p[2 * hk + 1][1]);
      unsigned v3 = cvt_pk_bf16(p[2 * hk + 1][2], p[2 * hk + 1][3]);
      #pragma unroll
      for (int wd = 0; wd < 4; wd++) {
        int src = (((g & 1) * 2 + (wd >> 1)) << 4) + l15;
        unsigned t0 = __shfl((wd & 1) ? v1 : v0, src, 64);
        unsigned t1 = __shfl((wd & 1) ? v3 : v2, src, 64);
        pbw[hk][wd] = (g < 2) ? t0 : t1;
      }
    }
    s16x8 pbv0 = *(s16x8*)pbw[0];
    s16x8 pbv1 = *(s16x8*)pbw[1];

    // PV: acco[dt] = O^T[d=dt*16+g*4+r][q=l15]
    __builtin_amdgcn_s_setprio(1);
    #pragma unroll
    for (int dt = 0; dt < 8; dt++) {
      int rr = dt * 16 + l15;
      int rs = rr * 128;
      int sw = (rr & 7) << 4;
      s16x8 vf0 = *(const s16x8*)(Vd + rs + ((g * 16) ^ sw));
      s16x8 vf1 = *(const s16x8*)(Vd + rs + ((64 + g * 16) ^ sw));
      acco[dt] = __builtin_amdgcn_mfma_f32_16x16x32_bf16(vf0, pbv0, acco[dt], 0, 0, 0);
      acco[dt] = __builtin_amdgcn_mfma_f32_16x16x32_bf16(vf1, pbv1, acco[dt], 0, 0, 0);
    }
    __builtin_amdgcn_s_setprio(0);
    __syncthreads();
    bbuf ^= 1;
  }

  // store l-normalized partial (bf16) + (m,l); s == bid
  float inv = 1.0f / lrun;
  ushort* ob = Opart + (size_t)bid * 8192 + (w * 16 + l15) * 128;
  #pragma unroll
  for (int dt = 0; dt < 8; dt++) {
    f32x4 o4 = acco[dt] * inv;
    uint2 st;
    st.x = cvt_pk_bf16(o4[0], o4[1]);
    st.y = cvt_pk_bf16(o4[2], o4[3]);
    *(uint2*)(ob + dt * 16 + g * 4) = st;
  }
  if (lane < 16) {
    Ml[(size_t)bid * 128 + (w * 16 + lane) * 2]     = mrun;
    Ml[(size_t)bid * 128 + (w * 16 + lane) * 2 + 1] = lrun;
  }
}

// ---------------------------------------------------------------------------
// Kernel 4: combine partials. Block (512 thr) per (b, 64-row q-block).
// ---------------------------------------------------------------------------
__global__ __launch_bounds__(512) void combine_kernel(
    const ushort* __restrict__ Opart, const float* __restrict__ Ml,
    float* __restrict__ out)
{
  const int bq = blockIdx.x;          // 0..255
  const int b = bq >> 5, j = bq & 31;
  const int a = j >> 2, jin = j & 3, nch = a + 1;
  const int s0 = b * 144 + 2 * a * (a + 1) + jin * (a + 1);
  const int tid = threadIdx.x;
  const int row = tid >> 3, ci = tid & 7;

  float M = -1e30f;
  for (int c = 0; c < nch; c++)
    M = fmaxf(M, Ml[(size_t)(s0 + c) * 128 + row * 2]);

  float acc[16];
  #pragma unroll
  for (int k = 0; k < 16; k++) acc[k] = 0.f;
  float W = 0.f;
  for (int c = 0; c < nch; c++) {
    float m = Ml[(size_t)(s0 + c) * 128 + row * 2];
    float l = Ml[(size_t)(s0 + c) * 128 + row * 2 + 1];
    float wgt = l * __expf(m - M);
    W += wgt;
    const ushort* vp = Opart + (size_t)(s0 + c) * 8192 + row * 128 + ci * 16;
    s16x8 v0 = *(const s16x8*)vp;
    s16x8 v1 = *(const s16x8*)(vp + 8);
    #pragma unroll
    for (int k = 0; k < 8; k++) {
      acc[k]     += wgt * bf2f((ushort)v0[k]);
      acc[8 + k] += wgt * bf2f((ushort)v1[k]);
    }
  }
  float invW = 1.0f / W;
  float* op = out + ((size_t)(b * 2048 + j * 64 + row)) * 128 + ci * 16;
  #pragma unroll
  for (int q = 0; q < 4; q++) {
    f32x4 o4 { acc[q*4]*invW, acc[q*4+1]*invW, acc[q*4+2]*invW, acc[q*4+3]*invW };
    *(f32x4*)(op + q * 4) = o4;
  }
}

// ---------------------------------------------------------------------------
extern "C" void kernel_launch(void* const* d_in, const int* in_sizes, int n_in,
                              void* d_out, int out_size, void* d_ws, size_t ws_size,
                              hipStream_t stream)
{
  const float* x    = (const float*)d_in[0];
  const float* cosp = (const float*)d_in[1];
  const float* sinp = (const float*)d_in[2];
  const float* Wk   = (const float*)d_in[3];
  const float* Wq   = (const float*)d_in[4];
  const float* Wv   = (const float*)d_in[5];
  char* ws = (char*)d_ws;
  ushort* xbf   = (ushort*)ws;                       // 33,554,432 B (dead after qkv)
  ushort* wt    = (ushort*)(ws + 33554432);          //    786,432 B
  ushort* Qw    = (ushort*)(ws + 34340864);          //  4,194,304 B
  ushort* Kw    = (ushort*)(ws + 38535168);          //  4,194,304 B
  ushort* VT    = (ushort*)(ws + 42729472);          //  4,194,304 B
  ushort* Opart = (ushort*)ws;                       // 18,874,368 B (aliases xbf)
  float*  Ml    = (float*)(ws + 18874368);           //    589,824 B (still in xbf)
  float* outp = (float*)d_out;

  prep_kernel<<<9728, 256, 0, stream>>>(x, Wk, Wq, Wv, xbf, wt);
  qkv_kernel<<<256, 512, 0, stream>>>(xbf, wt, cosp, sinp, Qw, Kw, VT);
  attn_kernel<<<1152, 256, 0, stream>>>(Qw, Kw, VT, Opart, Ml);
  combine_kernel<<<256, 512, 0, stream>>>(Opart, Ml, outp);
}

// Round 5
// 167.746 us; speedup vs baseline: 1.8138x; 1.0467x over previous
//
#include <hip/hip_runtime.h>

#define B_ 8
#define T_ 2048
#define C_ 1024
#define D_ 128

typedef __attribute__((ext_vector_type(4))) float f32x4;
typedef __attribute__((ext_vector_type(8))) short s16x8;

static __device__ __forceinline__ ushort f2bf(float f){
  unsigned u = __float_as_uint(f);
  u = (u + 0x7fffu + ((u >> 16) & 1u)) >> 16;   // RNE
  return (ushort)u;
}
static __device__ __forceinline__ float bf2f(ushort u){
  return __uint_as_float(((unsigned)u) << 16);
}
static __device__ __forceinline__ unsigned cvt_pk_bf16(float lo, float hi){
  unsigned r;
  asm volatile("v_cvt_pk_bf16_f32 %0, %1, %2" : "=v"(r) : "v"(lo), "v"(hi));
  return r;
}

// ---------------------------------------------------------------------------
// Kernel 1: wprep — W{q,k,v} f32 -> wt[384][1024] bf16 (transposed)
// ---------------------------------------------------------------------------
__global__ __launch_bounds__(256) void wprep_kernel(
    const float* __restrict__ Wk, const float* __restrict__ Wq, const float* __restrict__ Wv,
    ushort* __restrict__ wt)
{
  int j = blockIdx.x * 256 + threadIdx.x;     // 393,216 = 384*1024
  int n3 = j >> 10, k = j & 1023;
  int sel = n3 >> 7, n = n3 & 127;
  const float* W = (sel == 0) ? Wq : (sel == 1) ? Wk : Wv;
  wt[j] = f2bf(W[k * 128 + n]);               // wt[n3][k] = W[k][n]
}

// ---------------------------------------------------------------------------
// Kernel 2: qkv GEMM + RoPE. 512 thr (8 waves = 2m x 4n), tile 64x384, BK=64,
// double-buffered. A: reg-staged from f32 x (cvt in-flight, swizzled ds_write).
// B: global_load_lds (swizzled source). Loads for step t+1 fly under MFMA(t).
// ---------------------------------------------------------------------------
__global__ __launch_bounds__(512) void qkv_kernel(
    const float* __restrict__ x, const ushort* __restrict__ wt,
    const float* __restrict__ cosp, const float* __restrict__ sinp,
    ushort* __restrict__ Qw, ushort* __restrict__ Kw, ushort* __restrict__ VT)
{
  __shared__ __align__(16) ushort As[2][64 * 64];    // 2 x  8 KB
  __shared__ __align__(16) ushort Bs[2][384 * 64];   // 2 x 48 KB
  const int tid = threadIdx.x;
  const int m0  = blockIdx.x * 64;
  const int wid = tid >> 6, lane = tid & 63;
  const int wm = wid >> 2, wn = wid & 3;
  const int g = lane >> 4, l15 = lane & 15;

  f32x4 acc[2][6];
  #pragma unroll
  for (int i = 0; i < 2; i++)
    #pragma unroll
    for (int j = 0; j < 6; j++) acc[i][j] = f32x4{0.f, 0.f, 0.f, 0.f};

  // B staging: thread t fills LDS bytes [t*16, t*16+16) of each 64-row panel
  const int o = tid * 16;
  const int srow = o >> 7;
  const int scb  = (o & 127) ^ ((srow & 7) << 4);
  const char* wbase = (const char*)wt + (size_t)srow * 2048 + scb;
  // A staging: thread t loads 8 f32 of row (t>>3), col chunk (t&7)*8
  const int arow = tid >> 3;
  const int ac8  = (tid & 7) * 8;
  const float* xp = x + (size_t)(m0 + arow) * 1024 + ac8;
  const int adst = arow * 64 + (((tid & 7) * 8) ^ ((arow & 7) << 3));  // ushort units

  auto stageB = [&](int k0, int bb) {
    #pragma unroll
    for (int j = 0; j < 6; j++) {
      __builtin_amdgcn_global_load_lds(
          (const __attribute__((address_space(1))) void*)(wbase + (size_t)j * 64 * 2048 + k0 * 2),
          (__attribute__((address_space(3))) void*)((char*)Bs + bb * 49152 + j * 8192 + o), 16, 0, 0);
    }
  };
  auto writeA = [&](f32x4 a0, f32x4 a1, int bb) {
    unsigned aw[4];
    aw[0] = cvt_pk_bf16(a0[0], a0[1]);
    aw[1] = cvt_pk_bf16(a0[2], a0[3]);
    aw[2] = cvt_pk_bf16(a1[0], a1[1]);
    aw[3] = cvt_pk_bf16(a1[2], a1[3]);
    *(s16x8*)(&As[bb][adst]) = *(s16x8*)aw;
  };

  {
    f32x4 a0 = *(const f32x4*)(xp);
    f32x4 a1 = *(const f32x4*)(xp + 4);
    stageB(0, 0);
    writeA(a0, a1, 0);
  }
  __syncthreads();
  int bb = 0;
  for (int k0 = 0; k0 < 1024; k0 += 64) {
    int k1 = (k0 + 64 < 1024) ? k0 + 64 : 0;       // last iter: harmless reload
    f32x4 n0 = *(const f32x4*)(xp + k1);
    f32x4 n1 = *(const f32x4*)(xp + k1 + 4);
    stageB(k1, bb ^ 1);

    const char* Ab = (const char*)As + bb * 8192;
    const char* Bb = (const char*)Bs + bb * 49152;
    #pragma unroll
    for (int kk = 0; kk < 2; kk++) {
      s16x8 af[2];
      #pragma unroll
      for (int mi = 0; mi < 2; mi++) {
        int row = wm * 32 + mi * 16 + l15;
        int cb  = (kk * 64 + g * 16) ^ ((row & 7) << 4);
        af[mi] = *(const s16x8*)(Ab + row * 128 + cb);
      }
      s16x8 bfr[6];
      #pragma unroll
      for (int n = 0; n < 6; n++) {
        int col = wn * 96 + n * 16 + l15;
        int cb2 = (kk * 64 + g * 16) ^ ((col & 7) << 4);
        bfr[n] = *(const s16x8*)(Bb + col * 128 + cb2);
      }
      __builtin_amdgcn_s_setprio(1);
      #pragma unroll
      for (int mi = 0; mi < 2; mi++)
        #pragma unroll
        for (int n = 0; n < 6; n++)
          acc[mi][n] = __builtin_amdgcn_mfma_f32_16x16x32_bf16(af[mi], bfr[n], acc[mi][n], 0, 0, 0);
      __builtin_amdgcn_s_setprio(0);
    }
    writeA(n0, n1, bb ^ 1);
    __syncthreads();
    bb ^= 1;
  }

  // epilogue: C frag = (row = m0+wm*32+mi*16+g*4+r, col = wn*96+n*16+l15)
  const int rowb0 = m0 + wm * 32;
  #pragma unroll
  for (int mi = 0; mi < 2; mi++) {
    #pragma unroll
    for (int n = 0; n < 6; n++) {
      int colbase = wn * 96 + n * 16;
      int region  = colbase >> 7;            // 0=q 1=k 2=v
      int dcol    = (colbase & 127) + l15;
      int rowb    = rowb0 + mi * 16 + g * 4;
      if (region < 2) {
        ushort* dst = region ? Kw : Qw;
        int ii = dcol >> 1;
        float sgn = (dcol & 1) ? 1.0f : -1.0f;
        #pragma unroll
        for (int r = 0; r < 4; r++) {
          float own  = acc[mi][n][r];
          float part = __shfl_xor(own, 1, 64);
          int row = rowb + r;
          int t   = row & 2047;
          float c = cosp[t * 64 + ii], s = sinp[t * 64 + ii];
          float val = own * c + sgn * part * s;
          dst[row * 128 + dcol] = f2bf(val);
        }
      } else {
        int t0 = rowb & 2047;
        int b  = rowb >> 11;
        unsigned w0 = (unsigned)f2bf(acc[mi][n][0]) | ((unsigned)f2bf(acc[mi][n][1]) << 16);
        unsigned w1 = (unsigned)f2bf(acc[mi][n][2]) | ((unsigned)f2bf(acc[mi][n][3]) << 16);
        uint2 st; st.x = w0; st.y = w1;
        *(uint2*)(VT + (size_t)b * (128 * 2048) + dcol * 2048 + t0) = st;  // VT[b][d][t]
      }
    }
  }
}

// ---------------------------------------------------------------------------
// Kernel 3: split-KV causal flash attention. Block = (b, q-block of 128 rows
// [32/wave, 2 frags], kv-chunk of 256). KVBLK=64, double-buffered LDS K/V^T.
// 576 blocks x 256 thr. K/V-frags shared across both Q-frags (2x MFMA density).
// ---------------------------------------------------------------------------
__global__ __launch_bounds__(256) void attn_kernel(
    const ushort* __restrict__ Qw, const ushort* __restrict__ Kw,
    const ushort* __restrict__ VT, ushort* __restrict__ Opart,
    float* __restrict__ Ml)
{
  __shared__ __align__(16) ushort KVs[2][16384];   // per buf: K 16 KB + V^T 16 KB
  const int tid = threadIdx.x;
  const int w = tid >> 6, lane = tid & 63;
  const int g = lane >> 4, l15 = lane & 15;

  const int bid = blockIdx.x;
  const int b   = bid / 72;
  const int idx = bid - b * 72;
  int a = 0;
  #pragma unroll
  for (int t = 1; t < 8; t++) if (idx >= t * (t + 1)) a = t;
  const int rem = idx - a * (a + 1);
  const int jin = rem / (a + 1);
  const int c   = rem - jin * (a + 1);
  const int j   = 2 * a + jin;
  const int q0  = j * 128;
  const int kv_base = c * 256;
  const int kv_end  = min(kv_base + 256, q0 + 128);
  const int nt  = (kv_end - kv_base) >> 6;     // 1..4 full 64-row tiles
  int qg[2];
  qg[0] = q0 + w * 32 + l15;
  qg[1] = qg[0] + 16;

  const ushort* Qb = Qw + (size_t)b * T_ * 128;
  const char* Kbase = (const char*)(Kw + (size_t)b * T_ * 128);
  const char* Vbase = (const char*)(VT + (size_t)b * 128 * T_);

  auto stage = [&](int kv0, int bbuf) {
    char* Kd = (char*)&KVs[bbuf][0];
    char* Vd = (char*)&KVs[bbuf][8192];
    #pragma unroll
    for (int p = 0; p < 4; p++) {           // K: 64 rows x 256B, swizzled
      int oo = p * 4096 + tid * 16;
      int r = oo >> 8, cin = oo & 255;
      int cb = cin ^ ((r & 7) << 4);
      __builtin_amdgcn_global_load_lds(
          (const __attribute__((address_space(1))) void*)(Kbase + (size_t)(kv0 + r) * 256 + cb),
          (__attribute__((address_space(3))) void*)(Kd + oo), 16, 0, 0);
    }
    #pragma unroll
    for (int p = 0; p < 4; p++) {           // V^T: 128 rows x 128B, swizzled
      int oo = p * 4096 + tid * 16;
      int r = oo >> 7, cin = oo & 127;
      int cb = cin ^ ((r & 7) << 4);
      __builtin_amdgcn_global_load_lds(
          (const __attribute__((address_space(1))) void*)(Vbase + (size_t)r * 4096 + (size_t)kv0 * 2 + cb),
          (__attribute__((address_space(3))) void*)(Vd + oo), 16, 0, 0);
    }
  };

  s16x8 qf[2][4];
  #pragma unroll
  for (int i = 0; i < 2; i++)
    #pragma unroll
    for (int kd = 0; kd < 4; kd++)
      qf[i][kd] = *(const s16x8*)(Qb + (size_t)qg[i] * 128 + kd * 32 + g * 8);

  f32x4 acco[2][8];
  #pragma unroll
  for (int i = 0; i < 2; i++)
    #pragma unroll
    for (int d = 0; d < 8; d++) acco[i][d] = f32x4{0.f, 0.f, 0.f, 0.f};
  float mrun[2] = {-1e30f, -1e30f}, lrun[2] = {0.f, 0.f};
  const float scale = 0.08838834764831845f;   // 1/sqrt(128)

  stage(kv_base, 0);
  __syncthreads();
  int bbuf = 0;
  for (int t = 0; t < nt; t++) {
    int kv0 = kv_base + t * 64;
    if (t + 1 < nt) stage(kv0 + 64, bbuf ^ 1);
    const char* Kd = (const char*)&KVs[bbuf][0];
    const char* Vd = (const char*)&KVs[bbuf][8192];

    // QK^T (swapped): accs[i][h] = S^T[kv=h*16+g*4+r][q=l15] for q-frag i
    f32x4 accs[2][4];
    #pragma unroll
    for (int i = 0; i < 2; i++)
      #pragma unroll
      for (int h = 0; h < 4; h++) accs[i][h] = f32x4{0.f, 0.f, 0.f, 0.f};
    __builtin_amdgcn_s_setprio(1);
    #pragma unroll
    for (int h = 0; h < 4; h++) {
      int rr = h * 16 + l15;
      int rs = rr * 256;
      int sw = (rr & 7) << 4;
      #pragma unroll
      for (int kd = 0; kd < 4; kd++) {
        s16x8 kf = *(const s16x8*)(Kd + rs + ((kd * 64 + g * 16) ^ sw));
        accs[0][h] = __builtin_amdgcn_mfma_f32_16x16x32_bf16(kf, qf[0][kd], accs[0][h], 0, 0, 0);
        accs[1][h] = __builtin_amdgcn_mfma_f32_16x16x32_bf16(kf, qf[1][kd], accs[1][h], 0, 0, 0);
      }
    }
    __builtin_amdgcn_s_setprio(0);

    // online softmax (per q-frag): 16 kv values/lane, reduce across g via shfl
    s16x8 pbv[2][2];
    #pragma unroll
    for (int i = 0; i < 2; i++) {
      float p[4][4];
      float pmax = -1e30f;
      #pragma unroll
      for (int h = 0; h < 4; h++)
        #pragma unroll
        for (int r = 0; r < 4; r++) {
          int kvg = kv0 + h * 16 + g * 4 + r;
          float sv = accs[i][h][r] * scale;
          sv = (kvg <= qg[i]) ? sv : -1e30f;
          p[h][r] = sv;
          pmax = fmaxf(pmax, sv);
        }
      pmax = fmaxf(pmax, __shfl_xor(pmax, 16, 64));
      pmax = fmaxf(pmax, __shfl_xor(pmax, 32, 64));
      float mnew = fmaxf(mrun[i], pmax);
      float f = __expf(mrun[i] - mnew);
      float psum = 0.0f;
      #pragma unroll
      for (int h = 0; h < 4; h++)
        #pragma unroll
        for (int r = 0; r < 4; r++) { float e = __expf(p[h][r] - mnew); p[h][r] = e; psum += e; }
      psum += __shfl_xor(psum, 16, 64);
      psum += __shfl_xor(psum, 32, 64);
      lrun[i] = lrun[i] * f + psum;
      mrun[i] = mnew;
      #pragma unroll
      for (int d = 0; d < 8; d++) acco[i][d] *= f;

      // P remap -> two B-fragments (kv 0..31, 32..63 of tile)
      #pragma unroll
      for (int hk = 0; hk < 2; hk++) {
        unsigned v0 = cvt_pk_bf16(p[2 * hk][0], p[2 * hk][1]);
        unsigned v1 = cvt_pk_bf16(p[2 * hk][2], p[2 * hk][3]);
        unsigned v2 = cvt_pk_bf16(p[2 * hk + 1][0], p[2 * hk + 1][1]);
        unsigned v3 = cvt_pk_bf16(p[2 * hk + 1][2], p[2 * hk + 1][3]);
        unsigned pb[4];
        #pragma unroll
        for (int wd = 0; wd < 4; wd++) {
          int src = (((g & 1) * 2 + (wd >> 1)) << 4) + l15;
          unsigned t0 = __shfl((wd & 1) ? v1 : v0, src, 64);
          unsigned t1 = __shfl((wd & 1) ? v3 : v2, src, 64);
          pb[wd] = (g < 2) ? t0 : t1;
        }
        pbv[i][hk] = *(s16x8*)pb;
      }
    }

    // PV: acco[i][dt] = O^T[d=dt*16+g*4+r][q=l15]; V-frags shared across i
    __builtin_amdgcn_s_setprio(1);
    #pragma unroll
    for (int dt = 0; dt < 8; dt++) {
      int rr = dt * 16 + l15;
      int rs = rr * 128;
      int sw = (rr & 7) << 4;
      s16x8 vf0 = *(const s16x8*)(Vd + rs + ((g * 16) ^ sw));
      s16x8 vf1 = *(const s16x8*)(Vd + rs + ((64 + g * 16) ^ sw));
      acco[0][dt] = __builtin_amdgcn_mfma_f32_16x16x32_bf16(vf0, pbv[0][0], acco[0][dt], 0, 0, 0);
      acco[0][dt] = __builtin_amdgcn_mfma_f32_16x16x32_bf16(vf1, pbv[0][1], acco[0][dt], 0, 0, 0);
      acco[1][dt] = __builtin_amdgcn_mfma_f32_16x16x32_bf16(vf0, pbv[1][0], acco[1][dt], 0, 0, 0);
      acco[1][dt] = __builtin_amdgcn_mfma_f32_16x16x32_bf16(vf1, pbv[1][1], acco[1][dt], 0, 0, 0);
    }
    __builtin_amdgcn_s_setprio(0);
    __syncthreads();
    bbuf ^= 1;
  }

  // store l-normalized partials (bf16) + (m,l); partial slot == bid
  #pragma unroll
  for (int i = 0; i < 2; i++) {
    float inv = 1.0f / lrun[i];
    ushort* ob = Opart + (size_t)bid * 16384 + (w * 32 + i * 16 + l15) * 128;
    #pragma unroll
    for (int dt = 0; dt < 8; dt++) {
      f32x4 o4 = acco[i][dt] * inv;
      uint2 st;
      st.x = cvt_pk_bf16(o4[0], o4[1]);
      st.y = cvt_pk_bf16(o4[2], o4[3]);
      *(uint2*)(ob + dt * 16 + g * 4) = st;
    }
    if (lane < 16) {
      Ml[(size_t)bid * 256 + (w * 32 + i * 16 + lane) * 2]     = mrun[i];
      Ml[(size_t)bid * 256 + (w * 32 + i * 16 + lane) * 2 + 1] = lrun[i];
    }
  }
}

// ---------------------------------------------------------------------------
// Kernel 4: combine partials. Block (512 thr) per (b, 64-row half of q-block).
// ---------------------------------------------------------------------------
__global__ __launch_bounds__(512) void combine_kernel(
    const ushort* __restrict__ Opart, const float* __restrict__ Ml,
    float* __restrict__ out)
{
  const int bq = blockIdx.x;          // 0..255
  const int b = bq >> 5, h = bq & 31;
  const int j = h >> 1, half = h & 1;
  const int a = j >> 1, jin = j & 1, nch = a + 1;
  const int s0 = b * 72 + a * (a + 1) + jin * (a + 1);
  const int tid = threadIdx.x;
  const int row = half * 64 + (tid >> 3), ci = tid & 7;

  float M = -1e30f;
  for (int c = 0; c < nch; c++)
    M = fmaxf(M, Ml[(size_t)(s0 + c) * 256 + row * 2]);

  float acc[16];
  #pragma unroll
  for (int k = 0; k < 16; k++) acc[k] = 0.f;
  float W = 0.f;
  for (int c = 0; c < nch; c++) {
    float m = Ml[(size_t)(s0 + c) * 256 + row * 2];
    float l = Ml[(size_t)(s0 + c) * 256 + row * 2 + 1];
    float wgt = l * __expf(m - M);
    W += wgt;
    const ushort* vp = Opart + (size_t)(s0 + c) * 16384 + row * 128 + ci * 16;
    s16x8 v0 = *(const s16x8*)vp;
    s16x8 v1 = *(const s16x8*)(vp + 8);
    #pragma unroll
    for (int k = 0; k < 8; k++) {
      acc[k]     += wgt * bf2f((ushort)v0[k]);
      acc[8 + k] += wgt * bf2f((ushort)v1[k]);
    }
  }
  float invW = 1.0f / W;
  float* op = out + ((size_t)(b * 2048 + h * 64 + (tid >> 3))) * 128 + ci * 16;
  #pragma unroll
  for (int q = 0; q < 4; q++) {
    f32x4 o4 { acc[q*4]*invW, acc[q*4+1]*invW, acc[q*4+2]*invW, acc[q*4+3]*invW };
    *(f32x4*)(op + q * 4) = o4;
  }
}

// ---------------------------------------------------------------------------
extern "C" void kernel_launch(void* const* d_in, const int* in_sizes, int n_in,
                              void* d_out, int out_size, void* d_ws, size_t ws_size,
                              hipStream_t stream)
{
  const float* x    = (const float*)d_in[0];
  const float* cosp = (const float*)d_in[1];
  const float* sinp = (const float*)d_in[2];
  const float* Wk   = (const float*)d_in[3];
  const float* Wq   = (const float*)d_in[4];
  const float* Wv   = (const float*)d_in[5];
  char* ws = (char*)d_ws;
  ushort* wt    = (ushort*)ws;                       //    786,432 B
  ushort* Qw    = (ushort*)(ws + 1048576);           //  4,194,304 B
  ushort* Kw    = (ushort*)(ws + 5242880);           //  4,194,304 B
  ushort* VT    = (ushort*)(ws + 9437184);           //  4,194,304 B
  ushort* Opart = (ushort*)(ws + 13631488);          // 18,874,368 B
  float*  Ml    = (float*)(ws + 32505856);           //    589,824 B
  float* outp = (float*)d_out;

  wprep_kernel<<<1536, 256, 0, stream>>>(Wk, Wq, Wv, wt);
  qkv_kernel<<<256, 512, 0, stream>>>(x, wt, cosp, sinp, Qw, Kw, VT);
  attn_kernel<<<576, 256, 0, stream>>>(Qw, Kw, VT, Opart, Ml);
  combine_kernel<<<256, 512, 0, stream>>>(Opart, Ml, outp);
}